// Round 5
// baseline (205.190 us; speedup 1.0000x reference)
//
#include <hip/hip_runtime.h>

// YOLOv1 loss: pred/label (16384, 30, 7, 7) fp32 -> scalar.
// R4: latency-chain-bound diagnosis (dur invariant to HBM traffic; per-block
// lifetime ~20k cyc of serial waits). Fix: double-buffered async staging via
// __builtin_amdgcn_global_load_lds (width 16, m97 pattern) -- no vmcnt wait
// before ds_write, load latency hidden behind compute of previous chunk.
// 768 blocks (3/CU) x ~10 chunks each, per-thread accumulate, 1 store/block.

#define NBATCH 16384
#define NCH 30
#define NCELL 49        // 7*7
#define BSTRIDE 1470    // 30*49
#define BLOCK 256
#define NB 2            // batches per chunk
#define CHUNK (NB * BSTRIDE)    // 2940 floats per tensor per chunk
#define CHUNK4 (CHUNK / 4)      // 735 float4 (exact)
#define NCHUNKS (NBATCH / NB)   // 8192
#define GRID 768                // 3 blocks/CU * 256 CUs

typedef __attribute__((address_space(1))) const void gvoid;
typedef __attribute__((address_space(3))) void lvoid;

__device__ __forceinline__ float sq(float x) { return x * x; }

__device__ __forceinline__ float iou_vs_label(float x, float y, float w, float h,
                                              float fc, float fr,
                                              float lx1, float ly1, float lx2, float ly2,
                                              float larea) {
    const float inv7 = 1.0f / 7.0f;
    float cx = (x + fc) * inv7;
    float cy = (y + fr) * inv7;
    float hw = w * 0.5f, hh = h * 0.5f;
    float x1 = cx - hw, y1 = cy - hh;
    float x2 = cx + hw, y2 = cy + hh;
    float iw = fmaxf(fminf(x2, lx2) - fmaxf(x1, lx1), 0.0f);
    float ih = fmaxf(fminf(y2, ly2) - fmaxf(y1, ly1), 0.0f);
    float inter = iw * ih;
    float area = (x2 - x1) * (y2 - y1);
    return inter / (area + larea - inter + 1e-10f);
}

__global__ __launch_bounds__(BLOCK) void yolo_loss_main(const float* __restrict__ pred,
                                                        const float* __restrict__ label,
                                                        float* __restrict__ partials) {
    __shared__ float4 sp4[2][CHUNK4];
    __shared__ float4 sl4[2][CHUNK4];
    __shared__ float smem[BLOCK / 64];

    const int tid = threadIdx.x;

    // Async stage chunk c into buffer b. Fire-and-forget: no vmcnt wait here;
    // the compiler drains vmcnt(0) before the next s_barrier.
    auto stage = [&](int c, int b) {
        const float4* gp = (const float4*)(pred + (size_t)c * CHUNK);
        const float4* gl = (const float4*)(label + (size_t)c * CHUNK);
#pragma unroll
        for (int it = 0; it < 3; ++it) {
            int i = it * BLOCK + tid;
            if (i < CHUNK4) {
                __builtin_amdgcn_global_load_lds((gvoid*)(gp + i), (lvoid*)&sp4[b][i], 16, 0, 0);
                __builtin_amdgcn_global_load_lds((gvoid*)(gl + i), (lvoid*)&sl4[b][i], 16, 0, 0);
            }
        }
    };

    // Precompute per-thread cell geometry (constant across chunks).
    const int lb = tid / NCELL;          // batch within chunk (0..1) for tid<98
    const int rc = tid - lb * NCELL;
    const int r = rc / 7;
    const int c7 = rc - r * 7;
    const float fc = (float)c7, fr = (float)r;
    const float inv7 = 1.0f / 7.0f;
    const bool active = tid < NB * NCELL;

    float acc = 0.0f;

    int c = blockIdx.x;
    stage(c, 0);
    __syncthreads();
    int buf = 0;

    while (true) {
        int nextc = c + GRID;
        if (nextc < NCHUNKS) stage(nextc, buf ^ 1);

        if (active) {
            const float* sp = (const float*)&sp4[buf][0] + lb * BSTRIDE + rc;
            const float* sl = (const float*)&sl4[buf][0] + lb * BSTRIDE + rc;

            float p[NCH], l[NCH];
#pragma unroll
            for (int ch = 0; ch < NCH; ++ch) {
                p[ch] = sp[ch * NCELL];
                l[ch] = sl[ch * NCELL];
            }

            float lcx = (l[0] + fc) * inv7;
            float lcy = (l[1] + fr) * inv7;
            float lhw = l[2] * 0.5f, lhh = l[3] * 0.5f;
            float lx1 = lcx - lhw, ly1 = lcy - lhh;
            float lx2 = lcx + lhw, ly2 = lcy + lhh;
            float larea = (lx2 - lx1) * (ly2 - ly1);

            float iou1 = iou_vs_label(p[0], p[1], p[2], p[3], fc, fr, lx1, ly1, lx2, ly2, larea);
            float iou2 = iou_vs_label(p[5], p[6], p[7], p[8], fc, fr, lx1, ly1, lx2, ly2, larea);
            bool choose1 = iou1 >= iou2;

            float coord1 = 5.0f * (sq(p[0] - l[0]) + sq(p[1] - l[1]))
                         + sq(sqrtf(p[2]) - sqrtf(l[2])) + sq(sqrtf(p[3]) - sqrtf(l[3]));
            float coord2 = 5.0f * (sq(p[5] - l[5]) + sq(p[6] - l[6]))
                         + sq(sqrtf(p[7]) - sqrtf(l[7])) + sq(sqrtf(p[8]) - sqrtf(l[8]));

            float obj1 = sq(p[4] - iou1);
            float obj2 = sq(p[9] - iou2);

            float coord      = choose1 ? coord1 : coord2;
            float obj_conf   = choose1 ? obj1 : obj2;
            float noobj_conf = 0.5f * (choose1 ? obj2 : obj1);

            float class_l = 0.0f;
#pragma unroll
            for (int ch = 10; ch < NCH; ++ch) class_l += sq(p[ch] - l[ch]);

            float obj_cell = coord + obj_conf + noobj_conf + class_l;
            float psum = p[4] + p[9];
            float noobj_cell = 0.5f * psum * psum;

            acc += (l[4] == 1.0f) ? obj_cell : noobj_cell;
        }

        __syncthreads();   // drains async loads of next buffer; protects reuse
        if (nextc >= NCHUNKS) break;
        c = nextc;
        buf ^= 1;
    }

    // Block reduce of acc -> one plain store.
    float v = acc;
#pragma unroll
    for (int off = 32; off > 0; off >>= 1) v += __shfl_down(v, off, 64);

    const int lane = tid & 63;
    const int wave = tid >> 6;
    if (lane == 0) smem[wave] = v;
    __syncthreads();
    if (tid == 0) {
        partials[blockIdx.x] = smem[0] + smem[1] + smem[2] + smem[3];
    }
}

__global__ __launch_bounds__(BLOCK) void yolo_loss_reduce(const float* __restrict__ partials,
                                                          float* __restrict__ out) {
    float s = 0.0f;
#pragma unroll
    for (int it = 0; it < GRID / BLOCK; ++it)   // 3 independent loads
        s += partials[it * BLOCK + threadIdx.x];

#pragma unroll
    for (int off = 32; off > 0; off >>= 1) s += __shfl_down(s, off, 64);

    __shared__ float smem[BLOCK / 64];
    const int lane = threadIdx.x & 63;
    const int wave = threadIdx.x >> 6;
    if (lane == 0) smem[wave] = s;
    __syncthreads();
    if (threadIdx.x == 0) {
        out[0] = (smem[0] + smem[1] + smem[2] + smem[3]) * (1.0f / (float)NBATCH);
    }
}

extern "C" void kernel_launch(void* const* d_in, const int* in_sizes, int n_in,
                              void* d_out, int out_size, void* d_ws, size_t ws_size,
                              hipStream_t stream) {
    const float* pred  = (const float*)d_in[0];
    const float* label = (const float*)d_in[1];
    float* out = (float*)d_out;
    float* partials = (float*)d_ws;   // GRID floats = 3 KB scratch

    yolo_loss_main<<<GRID, BLOCK, 0, stream>>>(pred, label, partials);
    yolo_loss_reduce<<<1, BLOCK, 0, stream>>>(partials, out);
}